// Round 7
// baseline (555.544 us; speedup 1.0000x reference)
//
#include <hip/hip_runtime.h>

// SDPA fwd with materialized score. B=2,H=16,S=2048,D=128, fp32 in/out.
// Round-7 structure: preprocess to plain bf16 K [bh][s][d], bf16 V^T
// [bh][d][s], bitmask. Fused two-pass kernel with DIRECT global->VGPR
// fragment loads (no K/V LDS staging, no gll, no vmcnt counting):
//   pass 1: QK+exp+rowsum, ZERO barriers (waves fully independent).
//   pass 2: QK recompute + normalized score NT-stores + PV; LDS only for the
//           p~ exchange ([32][128] XOR-swizzled, dbuf) -> ONE lgkm barrier/iter.
// BKT=128, wave w owns k-cols/d-rows w*16..+15 for BOTH q-halves -> no
// duplicate K/V fragment loads across waves. XCD-affine block mapping keeps
// the per-bh working set (~2MB) L2-resident.
// Fallback (ws too small): round-1 kernel.

#define S_LEN 2048
#define DH 128
#define NT2 16                        // iterations, BKT=128
#define SCALE 0.088388347648318447f  // 1/sqrt(128)

typedef short short8_t __attribute__((ext_vector_type(8)));
typedef float f32x4_t __attribute__((ext_vector_type(4)));
typedef unsigned short u16x4_t __attribute__((ext_vector_type(4)));
typedef unsigned int u32x4_t __attribute__((ext_vector_type(4)));

__device__ __forceinline__ unsigned short f2bf(float x) {
  union { float f; unsigned u; } c; c.f = x;
  return (unsigned short)((c.u + 0x7FFFu + ((c.u >> 16) & 1u)) >> 16);  // RNE
}
__device__ __forceinline__ float bf2f(unsigned short b) {
  union { float f; unsigned u; } c; c.u = ((unsigned)b) << 16;
  return c.f;
}
__device__ __forceinline__ unsigned pk2(unsigned short a, unsigned short b) {
  return (unsigned)a | ((unsigned)b << 16);
}

// ---------------- preprocess kernels ----------------

// mask int32 -> bitmask u64 words: bm[(b*2048+row)*32 + w] bit l = (M[..w*64+l]!=0)
__global__ void pack_mask_k(const int* __restrict__ M, unsigned long long* __restrict__ bm) {
  int g = (blockIdx.x * 256 + threadIdx.x) >> 6;
  int lane = threadIdx.x & 63;
#pragma unroll
  for (int i = 0; i < 16; ++i) {
    int w = g * 16 + i;
    int v = M[(size_t)w * 64 + lane];
    unsigned long long bits = __ballot(v != 0);
    if (lane == 0) bm[w] = bits;
  }
}

// K fp32 -> bf16, same row-major layout (pure streaming convert)
__global__ void conv_kb(const float* __restrict__ K, unsigned short* __restrict__ kb) {
  size_t i = ((size_t)blockIdx.x * 256 + threadIdx.x) * 8;
  f32x4_t a = *(const f32x4_t*)(K + i);
  f32x4_t b = *(const f32x4_t*)(K + i + 4);
  u32x4_t o = { pk2(f2bf(a[0]), f2bf(a[1])), pk2(f2bf(a[2]), f2bf(a[3])),
                pk2(f2bf(b[0]), f2bf(b[1])), pk2(f2bf(b[2]), f2bf(b[3])) };
  *(u32x4_t*)(kb + i) = o;
}

// V fp32 [bh][s][d] -> V^T bf16 [bh][d][s] (transpose via LDS, 64-k tiles)
__global__ void conv_vt(const float* __restrict__ V, unsigned short* __restrict__ vtw) {
  __shared__ unsigned short t[64 * 132];
  int tile = blockIdx.x, bh = tile >> 5, kt = tile & 31, k0 = kt * 64;
  int tid = threadIdx.x;
  const float* src = V + ((size_t)bh * S_LEN + k0) * DH;
#pragma unroll
  for (int pass = 0; pass < 8; ++pass) {
    int idx = pass * 256 + tid;
    int row = idx >> 5, d0 = (idx & 31) * 4;
    f32x4_t a = *(const f32x4_t*)(src + (size_t)row * DH + d0);
    u16x4_t w = { f2bf(a[0]), f2bf(a[1]), f2bf(a[2]), f2bf(a[3]) };
    *(u16x4_t*)&t[row * 132 + d0] = w;
  }
  __syncthreads();
  int d = tid >> 1, h = (tid & 1) * 32;
  unsigned short tmp[32];
#pragma unroll
  for (int i = 0; i < 32; ++i) tmp[i] = t[(h + i) * 132 + d];
  unsigned short* dst = vtw + ((size_t)(bh * DH + d)) * S_LEN + k0 + h;
#pragma unroll
  for (int q = 0; q < 4; ++q) {
    u32x4_t o = { pk2(tmp[q*8+0], tmp[q*8+1]), pk2(tmp[q*8+2], tmp[q*8+3]),
                  pk2(tmp[q*8+4], tmp[q*8+5]), pk2(tmp[q*8+6], tmp[q*8+7]) };
    *(u32x4_t*)(dst + q * 8) = o;
  }
}

// ---------------- fused two-pass attention kernel ----------------

__global__ __launch_bounds__(512, 4)
void sdpa_fused(const float* __restrict__ Q,
                const unsigned short* __restrict__ KB,
                const unsigned short* __restrict__ VT,
                const unsigned long long* __restrict__ bm,
                float* __restrict__ Out, float* __restrict__ Sc) {
  // p~ tile [32 rows][128 cols] bf16, row stride 256B, XOR-16 swizzle:
  // phys_byte(row, x) = row*256 + (x ^ ((row&7)<<4)); dbuf.
  __shared__ unsigned short pb[2][32 * 128];
  __shared__ float lpart[8][32];
  __shared__ float rinv[32];

  const int tid = threadIdx.x;
  const int lane = tid & 63, w = tid >> 6;     // wave id = k/d sixteenth
  const int lg = lane >> 4, ln = lane & 15;

  // XCD-affine mapping (bijective, 2048 blocks): XCD x owns bh in [4x,4x+4).
  const int wg = blockIdx.x;
  const int j = wg >> 3;
  const int bh = (wg & 7) * 4 + (j >> 6);
  const int qt = j & 63;
  const int b = bh >> 4;
  const int q0 = qt * 32;

  // Q fragments for BOTH q-halves (A-operand): qf[qh][kk]
  short8_t qf[2][4];
#pragma unroll
  for (int qh = 0; qh < 2; ++qh) {
    const float* qrow = Q + ((size_t)bh * S_LEN + q0 + qh * 16 + ln) * DH;
#pragma unroll
    for (int kk = 0; kk < 4; ++kk) {
      f32x4_t a = *(const f32x4_t*)(qrow + kk * 32 + lg * 8);
      f32x4_t c = *(const f32x4_t*)(qrow + kk * 32 + lg * 8 + 4);
      short8_t f;
#pragma unroll
      for (int jj = 0; jj < 4; ++jj) { f[jj] = (short)f2bf(a[jj]); f[4 + jj] = (short)f2bf(c[jj]); }
      qf[qh][kk] = f;
    }
  }

  const unsigned short* kbb = KB + (size_t)bh * S_LEN * DH;   // [2048][128]
  const unsigned short* vtb = VT + (size_t)bh * DH * S_LEN;   // [128][2048]
  const unsigned long long* bmq = bm + ((size_t)b * S_LEN + q0) * 32;
  const int bitp = (w * 16 + ln) & 63;   // mask bit for this lane's k-col
  const int mwo = w >> 2;                // mask word offset within the 2/iter

  // ===== pass 1: QK + exp + row sums — ZERO barriers =====
  float psum[8] = {0.f, 0.f, 0.f, 0.f, 0.f, 0.f, 0.f, 0.f};
#pragma unroll 2
  for (int kt = 0; kt < NT2; ++kt) {
    const unsigned short* kp = kbb + (size_t)(kt * 128 + w * 16 + ln) * DH;
    f32x4_t a0 = {0.f, 0.f, 0.f, 0.f}, a1 = {0.f, 0.f, 0.f, 0.f};
#pragma unroll
    for (int kk = 0; kk < 4; ++kk) {
      short8_t kf = *(const short8_t*)(kp + kk * 32 + lg * 8);
      a0 = __builtin_amdgcn_mfma_f32_16x16x32_bf16(qf[0][kk], kf, a0, 0, 0, 0);
      a1 = __builtin_amdgcn_mfma_f32_16x16x32_bf16(qf[1][kk], kf, a1, 0, 0, 0);
    }
#pragma unroll
    for (int r = 0; r < 8; ++r) {
      int row = (r >> 2) * 16 + lg * 4 + (r & 3);
      unsigned long long mw = bmq[(size_t)row * 32 + kt * 2 + mwo];
      float s = (r < 4) ? a0[r & 3] : a1[r & 3];
      float p = ((mw >> bitp) & 1) ? __expf(s * SCALE) : 1.0f;  // exp(1e-9)==1.0f
      psum[r] += p;
    }
  }
  // reduce over the 16 ln-lanes (stays within lg group)
#pragma unroll
  for (int off = 1; off < 16; off <<= 1) {
#pragma unroll
    for (int r = 0; r < 8; ++r) psum[r] += __shfl_xor(psum[r], off, 64);
  }
  if (ln == 0) {
#pragma unroll
    for (int r = 0; r < 8; ++r)
      lpart[w][(r >> 2) * 16 + lg * 4 + (r & 3)] = psum[r];
  }
  __syncthreads();
  if (tid < 32) {
    float s = 0.f;
#pragma unroll
    for (int ww = 0; ww < 8; ++ww) s += lpart[ww][tid];
    rinv[tid] = 1.0f / s;
  }
  __syncthreads();

  // ===== pass 2: QK recompute + score NT-stores + PV — one barrier/iter =====
  const int sr = tid >> 4, sc8 = (tid & 15) * 8;
  const float ri_s = rinv[sr];
  float* scp = Sc + ((size_t)bh * S_LEN + q0 + sr) * S_LEN + sc8;
  f32x4_t o0 = {0.f, 0.f, 0.f, 0.f}, o1 = {0.f, 0.f, 0.f, 0.f};

#pragma unroll 2
  for (int kt = 0; kt < NT2; ++kt) {
    unsigned short* pbc = pb[kt & 1];
    // QK (bit-identical to pass 1)
    const unsigned short* kp = kbb + (size_t)(kt * 128 + w * 16 + ln) * DH;
    f32x4_t a0 = {0.f, 0.f, 0.f, 0.f}, a1 = {0.f, 0.f, 0.f, 0.f};
#pragma unroll
    for (int kk = 0; kk < 4; ++kk) {
      short8_t kf = *(const short8_t*)(kp + kk * 32 + lg * 8);
      a0 = __builtin_amdgcn_mfma_f32_16x16x32_bf16(qf[0][kk], kf, a0, 0, 0, 0);
      a1 = __builtin_amdgcn_mfma_f32_16x16x32_bf16(qf[1][kk], kf, a1, 0, 0, 0);
    }
    // p~ -> swizzled LDS tile
#pragma unroll
    for (int r = 0; r < 8; ++r) {
      int row = (r >> 2) * 16 + lg * 4 + (r & 3);
      unsigned long long mw = bmq[(size_t)row * 32 + kt * 2 + mwo];
      float s = (r < 4) ? a0[r & 3] : a1[r & 3];
      float p = ((mw >> bitp) & 1) ? __expf(s * SCALE) : 1.0f;
      *(unsigned short*)((char*)pbc + row * 256 +
                         ((((w * 16 + ln) << 1)) ^ ((row & 7) << 4))) = f2bf(p);
    }
    // publish p~ to the block (LDS-only drain; global loads/stores keep flowing)
    asm volatile("s_waitcnt lgkmcnt(0)\n\ts_barrier" ::: "memory");
    __builtin_amdgcn_sched_barrier(0);
    // normalized score write for this 128-col stripe (streaming)
    {
      short8_t pw = *(const short8_t*)((char*)pbc + sr * 256 +
                                       ((sc8 * 2) ^ ((sr & 7) << 4)));
      f32x4_t s0 = { bf2f((unsigned short)pw[0]) * ri_s, bf2f((unsigned short)pw[1]) * ri_s,
                     bf2f((unsigned short)pw[2]) * ri_s, bf2f((unsigned short)pw[3]) * ri_s };
      f32x4_t s1 = { bf2f((unsigned short)pw[4]) * ri_s, bf2f((unsigned short)pw[5]) * ri_s,
                     bf2f((unsigned short)pw[6]) * ri_s, bf2f((unsigned short)pw[7]) * ri_s };
      __builtin_nontemporal_store(s0, (f32x4_t*)(scp + kt * 128));
      __builtin_nontemporal_store(s1, (f32x4_t*)(scp + kt * 128 + 4));
    }
    // PV: d-rows w*16..+15, contraction over this iter's 128 k
    const unsigned short* vp = vtb + (size_t)(w * 16 + ln) * S_LEN + kt * 128;
#pragma unroll
    for (int ks = 0; ks < 4; ++ks) {
      short8_t vf = *(const short8_t*)(vp + ks * 32 + lg * 8);
      short8_t af0 = *(const short8_t*)((char*)pbc + ln * 256 +
                                        ((ks * 64 + lg * 16) ^ ((ln & 7) << 4)));
      short8_t af1 = *(const short8_t*)((char*)pbc + (16 + ln) * 256 +
                                        ((ks * 64 + lg * 16) ^ ((ln & 7) << 4)));
      o0 = __builtin_amdgcn_mfma_f32_16x16x32_bf16(af0, vf, o0, 0, 0, 0);
      o1 = __builtin_amdgcn_mfma_f32_16x16x32_bf16(af1, vf, o1, 0, 0, 0);
    }
    // no trailing barrier: dbuf + the one barrier above make next iter's
    // writes (other buffer) and the kt+2 reuse provably race-free.
  }

  // Out epilogue (nontemporal): o0/o1 cols = d = w*16+ln, rows = lg*4+j per half
#pragma unroll
  for (int r = 0; r < 8; ++r) {
    int rrow = (r >> 2) * 16 + lg * 4 + (r & 3);
    float val = ((r < 4) ? o0[r & 3] : o1[r & 3]) * rinv[rrow];
    size_t o = ((size_t)bh * S_LEN + q0 + rrow) * DH + w * 16 + ln;
    __builtin_nontemporal_store(val, &Out[o]);
  }
}

// ---------------- round-1 kernel (fallback when ws too small) ----------------

#define PT_STRIDE 2056
#define KLDS_STRIDE 136
#define VT_STRIDE 72

__global__ __launch_bounds__(512, 1)
void sdpa_kernel_v1(const float* __restrict__ Q, const float* __restrict__ K,
                    const float* __restrict__ V, const int* __restrict__ M,
                    float* __restrict__ Out, float* __restrict__ Sc) {
  extern __shared__ char smem[];
  unsigned short* pt  = (unsigned short*)smem;
  unsigned short* kvb = (unsigned short*)(smem + 131584);
  float* lpart2 = (float*)(smem + 131584 + 18432);
  float* rinv2  = lpart2 + 128;

  const int tid  = threadIdx.x;
  const int lane = tid & 63;
  const int wid  = tid >> 6;
  const int qh = wid >> 2, kq = wid & 3;
  const int lg = lane >> 4, ln = lane & 15;

  const int bid = blockIdx.x;
  const int qt = bid & 63, bh = bid >> 6, b = bh >> 4;
  const int q0 = qt * 32;

  const float* Qb = Q + ((size_t)bh * S_LEN + q0) * DH;
  const float* Kb = K + (size_t)bh * S_LEN * DH;
  const float* Vb = V + (size_t)bh * S_LEN * DH;
  const int*   Mb = M + ((size_t)b * S_LEN + q0) * (size_t)S_LEN;

  short8_t qf[4];
  {
    const float* qrow = Qb + (qh * 16 + ln) * DH;
#pragma unroll
    for (int kk = 0; kk < 4; ++kk) {
      f32x4_t a = *(const f32x4_t*)(qrow + kk * 32 + lg * 8);
      f32x4_t c = *(const f32x4_t*)(qrow + kk * 32 + lg * 8 + 4);
      short8_t f;
#pragma unroll
      for (int jj = 0; jj < 4; ++jj) { f[jj] = (short)f2bf(a[jj]); f[4 + jj] = (short)f2bf(c[jj]); }
      qf[kk] = f;
    }
  }

  float psum[4] = {0.f, 0.f, 0.f, 0.f};

  for (int kt = 0; kt < 32; ++kt) {
    const int k0 = kt * 64;
    __syncthreads();
#pragma unroll
    for (int p = 0; p < 4; ++p) {
      int idx = (p << 11) | (tid << 2);
      int r = idx >> 7, d0 = idx & 127;
      f32x4_t val = *(const f32x4_t*)(Kb + (size_t)(k0 + r) * DH + d0);
      u16x4_t w = { f2bf(val[0]), f2bf(val[1]), f2bf(val[2]), f2bf(val[3]) };
      *(u16x4_t*)&kvb[r * KLDS_STRIDE + d0] = w;
    }
    __syncthreads();

    const int kcol = k0 + kq * 16 + ln;
    int mv[4];
#pragma unroll
    for (int jj = 0; jj < 4; ++jj)
      mv[jj] = Mb[(size_t)(qh * 16 + lg * 4 + jj) * S_LEN + kcol];

    f32x4_t acc = {0.f, 0.f, 0.f, 0.f};
#pragma unroll
    for (int kk = 0; kk < 4; ++kk) {
      short8_t bf = *(short8_t*)&kvb[(kq * 16 + ln) * KLDS_STRIDE + kk * 32 + lg * 8];
      acc = __builtin_amdgcn_mfma_f32_16x16x32_bf16(qf[kk], bf, acc, 0, 0, 0);
    }
#pragma unroll
    for (int jj = 0; jj < 4; ++jj) {
      float p = mv[jj] ? __expf(acc[jj] * SCALE) : 1.0f;
      psum[jj] += p;
      pt[(qh * 16 + lg * 4 + jj) * PT_STRIDE + kcol] = f2bf(p);
    }
  }

#pragma unroll
  for (int off = 1; off < 16; off <<= 1) {
#pragma unroll
    for (int jj = 0; jj < 4; ++jj) psum[jj] += __shfl_xor(psum[jj], off, 64);
  }
  if (ln == 0) {
#pragma unroll
    for (int jj = 0; jj < 4; ++jj) lpart2[kq * 32 + qh * 16 + lg * 4 + jj] = psum[jj];
  }
  __syncthreads();
  if (tid < 32)
    rinv2[tid] = 1.0f / (lpart2[tid] + lpart2[32 + tid] + lpart2[64 + tid] + lpart2[96 + tid]);
  __syncthreads();

  {
    float* srow = Sc + ((size_t)bh * S_LEN + q0) * (size_t)S_LEN;
#pragma unroll 4
    for (int r = 0; r < 32; ++r) {
      float ri = rinv2[r];
      u16x4_t w = *(u16x4_t*)&pt[r * PT_STRIDE + tid * 4];
      f32x4_t o = { bf2f(w[0]) * ri, bf2f(w[1]) * ri, bf2f(w[2]) * ri, bf2f(w[3]) * ri };
      *(f32x4_t*)(srow + (size_t)r * S_LEN + tid * 4) = o;
    }
  }

  const int dq = kq;
  f32x4_t oacc0 = {0.f,0.f,0.f,0.f}, oacc1 = {0.f,0.f,0.f,0.f};
  const int dcol = tid & 127, qq = tid >> 7;
  for (int vt = 0; vt < 32; ++vt) {
    const int k0 = vt * 64;
    __syncthreads();
#pragma unroll
    for (int p = 0; p < 4; ++p) {
      int krb = p * 16 + qq * 4;
      const float* vp = Vb + (size_t)(k0 + krb) * DH + dcol;
      float v0 = vp[0], v1 = vp[DH], v2 = vp[2 * DH], v3 = vp[3 * DH];
      u16x4_t w = { f2bf(v0), f2bf(v1), f2bf(v2), f2bf(v3) };
      *(u16x4_t*)&kvb[dcol * VT_STRIDE + krb] = w;
    }
    __syncthreads();
#pragma unroll
    for (int ks = 0; ks < 2; ++ks) {
      short8_t af = *(short8_t*)&pt[(qh * 16 + ln) * PT_STRIDE + k0 + ks * 32 + lg * 8];
#pragma unroll
      for (int nb = 0; nb < 2; ++nb) {
        short8_t bf = *(short8_t*)&kvb[(dq * 32 + nb * 16 + ln) * VT_STRIDE + ks * 32 + lg * 8];
        if (nb == 0) oacc0 = __builtin_amdgcn_mfma_f32_16x16x32_bf16(af, bf, oacc0, 0, 0, 0);
        else         oacc1 = __builtin_amdgcn_mfma_f32_16x16x32_bf16(af, bf, oacc1, 0, 0, 0);
      }
    }
  }
#pragma unroll
  for (int jj = 0; jj < 4; ++jj) {
    int row = qh * 16 + lg * 4 + jj;
    float ri = rinv2[row];
    size_t o = ((size_t)bh * S_LEN + q0 + row) * DH + dq * 32 + ln;
    Out[o]      = oacc0[jj] * ri;
    Out[o + 16] = oacc1[jj] * ri;
  }
}

// ---------------- launcher ----------------

extern "C" void kernel_launch(void* const* d_in, const int* in_sizes, int n_in,
                              void* d_out, int out_size, void* d_ws, size_t ws_size,
                              hipStream_t stream) {
  const float* q = (const float*)d_in[0];
  const float* k = (const float*)d_in[1];
  const float* v = (const float*)d_in[2];
  const int*   m = (const int*)d_in[3];
  float* out = (float*)d_out;
  float* sc  = out + (size_t)2 * 16 * S_LEN * DH;

  const size_t BM_BYTES = 1u << 20;                 // bitmask, 1 MiB
  const size_t KB_BYTES = (size_t)2 * 16 * S_LEN * DH * 2;  // 16 MiB bf16 K
  const size_t NEED = BM_BYTES + 2 * KB_BYTES;      // ~33 MiB

  if (ws_size >= NEED) {
    unsigned long long* bm = (unsigned long long*)d_ws;
    unsigned short* kb = (unsigned short*)((char*)d_ws + BM_BYTES);
    unsigned short* vt = (unsigned short*)((char*)d_ws + BM_BYTES + KB_BYTES);

    pack_mask_k<<<dim3(2048), dim3(256), 0, stream>>>(m, bm);
    conv_kb<<<dim3(4096), dim3(256), 0, stream>>>(k, kb);
    conv_vt<<<dim3(1024), dim3(256), 0, stream>>>(v, vt);

    sdpa_fused<<<dim3(2048), dim3(512), 0, stream>>>(q, kb, vt, bm, out, sc);
  } else {
    const int smem = 131584 + 18432 + 512 + 128;
    hipFuncSetAttribute((const void*)sdpa_kernel_v1,
                        hipFuncAttributeMaxDynamicSharedMemorySize, smem);
    sdpa_kernel_v1<<<dim3(2048), dim3(512), smem, stream>>>(q, k, v, m, out, sc);
  }
}

// Round 8
// 335.846 us; speedup vs baseline: 1.6542x; 1.6542x over previous
//
#include <hip/hip_runtime.h>

// SDPA fwd with materialized score. B=2,H=16,S=2048,D=128, fp32 in/out.
// Round-8 = round-6 base (best: 307us) + pass-2 tweaks:
//  - p~ exchange triple-buffered; score written in 512B-contiguous batches
//    (tiles kt-1,kt together on odd iters) -> fewer, burst-friendly NT stores
//    with ~1.3-iter completion slack.
//  - uniform counted barriers: vmcnt(4) even iters / vmcnt(6) odd.
//  - s_setprio(1) around MFMA clusters.
// Pass 1 and preprocess identical to round 6 (verified counts).
// Fallback (ws too small): round-1 kernel.

#define S_LEN 2048
#define DH 128
#define NT 32
#define SCALE 0.088388347648318447f  // 1/sqrt(128)

typedef short short8_t __attribute__((ext_vector_type(8)));
typedef float f32x4_t __attribute__((ext_vector_type(4)));
typedef unsigned short u16x4_t __attribute__((ext_vector_type(4)));
typedef unsigned int u32x4_t __attribute__((ext_vector_type(4)));

__device__ __forceinline__ unsigned short f2bf(float x) {
  union { float f; unsigned u; } c; c.f = x;
  return (unsigned short)((c.u + 0x7FFFu + ((c.u >> 16) & 1u)) >> 16);  // RNE
}
__device__ __forceinline__ float bf2f(unsigned short b) {
  union { float f; unsigned u; } c; c.u = ((unsigned)b) << 16;
  return c.f;
}
__device__ __forceinline__ void gll16(const void* g, void* l) {
  __builtin_amdgcn_global_load_lds(
      (const __attribute__((address_space(1))) unsigned int*)g,
      (__attribute__((address_space(3))) unsigned int*)l, 16, 0, 0);
}
__device__ __forceinline__ unsigned pk2(unsigned short a, unsigned short b) {
  return (unsigned)a | ((unsigned)b << 16);
}

// ---------------- preprocess kernels ----------------

__global__ void pack_mask_k(const int* __restrict__ M, unsigned long long* __restrict__ bm) {
  int g = (blockIdx.x * 256 + threadIdx.x) >> 6;
  int lane = threadIdx.x & 63;
#pragma unroll
  for (int i = 0; i < 16; ++i) {
    int w = g * 16 + i;
    int v = M[(size_t)w * 64 + lane];
    unsigned long long bits = __ballot(v != 0);
    if (lane == 0) bm[w] = bits;
  }
}

__global__ void conv_k_k(const float* __restrict__ K, unsigned short* __restrict__ kws) {
  int c = blockIdx.x * 256 + threadIdx.x;
  int tile = c >> 10;
  int p = (c & 1023) * 16;
  int r = p >> 8, X = p & 255;
  int d0 = (X ^ ((r & 7) << 4)) >> 1;
  int bh = tile >> 5, k = (tile & 31) * 64 + r;
  const float* src = K + ((size_t)bh * S_LEN + k) * DH + d0;
  f32x4_t a = *(const f32x4_t*)src;
  f32x4_t b = *(const f32x4_t*)(src + 4);
  u32x4_t o = { pk2(f2bf(a[0]), f2bf(a[1])), pk2(f2bf(a[2]), f2bf(a[3])),
                pk2(f2bf(b[0]), f2bf(b[1])), pk2(f2bf(b[2]), f2bf(b[3])) };
  *(u32x4_t*)((char*)kws + (size_t)tile * 16384 + p) = o;
}

__global__ void conv_v_k(const float* __restrict__ V, unsigned short* __restrict__ vws) {
  __shared__ unsigned short vt[64 * 132];
  int tile = blockIdx.x, bh = tile >> 5, kt = tile & 31;
  int tid = threadIdx.x;
  const float* src = V + ((size_t)bh * S_LEN + kt * 64) * DH;
#pragma unroll
  for (int pass = 0; pass < 8; ++pass) {
    int idx = pass * 256 + tid;
    int row = idx >> 5, d0 = (idx & 31) * 4;
    f32x4_t a = *(const f32x4_t*)(src + (size_t)row * DH + d0);
    u16x4_t w = { f2bf(a[0]), f2bf(a[1]), f2bf(a[2]), f2bf(a[3]) };
    *(u16x4_t*)&vt[row * 132 + d0] = w;
  }
  __syncthreads();
#pragma unroll
  for (int c4 = 0; c4 < 4; ++c4) {
    int chunk = c4 * 256 + tid;
    int p = chunk * 16;
    int d = p >> 7, X = p & 127;
    int kv0 = (X ^ ((d & 7) << 4)) >> 1;
    unsigned short e[8];
#pragma unroll
    for (int i = 0; i < 8; ++i) e[i] = vt[(kv0 + i) * 132 + d];
    u32x4_t o = { pk2(e[0], e[1]), pk2(e[2], e[3]), pk2(e[4], e[5]), pk2(e[6], e[7]) };
    *(u32x4_t*)((char*)vws + (size_t)tile * 16384 + p) = o;
  }
}

// ---------------- fused two-pass attention kernel ----------------

__global__ __launch_bounds__(512, 4)
void sdpa_fused(const float* __restrict__ Q,
                const unsigned short* __restrict__ kws,
                const unsigned short* __restrict__ vws,
                const unsigned long long* __restrict__ bm,
                float* __restrict__ Out, float* __restrict__ Sc) {
  extern __shared__ char smem[];
  char* kst = smem;                                   // 4 x 16384 staging
  unsigned short* pbB = (unsigned short*)(smem + 65536);  // 3 x [32][72] bf16
  float* lpart = (float*)(smem + 65536 + 13824);      // [4][32]
  float* rinv  = lpart + 128;                         // [32]

  const int tid = threadIdx.x;
  const int lane = tid & 63, wid = tid >> 6;
  const int qh = wid >> 2, kq = wid & 3;
  const int lg = lane >> 4, ln = lane & 15;

  // XCD-affine mapping: XCD x (= wg&7) owns bh in [4x,4x+4) -> K/V L2-resident.
  const int wg = blockIdx.x;
  const int j = wg >> 3;
  const int bh = (wg & 7) * 4 + (j >> 6);
  const int qt = j & 63;
  const int b = bh >> 4;
  const int q0 = qt * 32;

  // Q fragments (fp32 -> bf16, registers for whole kernel)
  short8_t qf[4];
  {
    const float* qrow = Q + ((size_t)bh * S_LEN + q0 + qh * 16 + ln) * DH;
#pragma unroll
    for (int kk = 0; kk < 4; ++kk) {
      f32x4_t a = *(const f32x4_t*)(qrow + kk * 32 + lg * 8);
      f32x4_t c = *(const f32x4_t*)(qrow + kk * 32 + lg * 8 + 4);
      short8_t f;
#pragma unroll
      for (int jj = 0; jj < 4; ++jj) { f[jj] = (short)f2bf(a[jj]); f[4 + jj] = (short)f2bf(c[jj]); }
      qf[kk] = f;
    }
  }

  const char* ktiles = (const char*)kws + (size_t)bh * NT * 16384;
  const char* vtiles = (const char*)vws + (size_t)bh * NT * 16384;
  const int stoff = wid * 1024 + lane * 16;   // per-lane global offset
  const int ldoff = wid * 1024;               // wave-uniform LDS offset

  const unsigned long long* bmr = bm + ((size_t)b * S_LEN + q0 + qh * 16 + lg * 4) * NT;
  const int krow = kq * 16 + ln;
  const int arow = qh * 16 + ln;
  const int bitp = kq * 16 + ln;
  const int pbase = (qh * 16 + lg * 4) * 72 + kq * 16 + ln;

  float psum[4] = {0.f, 0.f, 0.f, 0.f};

  // ===== pass 1: QK + exp + row sums. K tiles 4-deep in 64KB staging LDS =====
  // (identical to round 6 — verified vmcnt accounting, see comments there)
  gll16(ktiles + stoff,                 kst + ldoff);
  gll16(ktiles + stoff + 8192,          kst + ldoff + 8192);
  gll16(ktiles + 16384 + stoff,         kst + 16384 + ldoff);
  gll16(ktiles + 16384 + stoff + 8192,  kst + 16384 + ldoff + 8192);
  gll16(ktiles + 32768 + stoff,         kst + 32768 + ldoff);
  gll16(ktiles + 32768 + stoff + 8192,  kst + 32768 + ldoff + 8192);
  __builtin_amdgcn_sched_barrier(0);
  unsigned long long ma0 = bmr[0], ma1 = bmr[NT], ma2 = bmr[2 * NT], ma3 = bmr[3 * NT];
  asm volatile("s_waitcnt vmcnt(8) lgkmcnt(0)\n\ts_barrier" ::: "memory");
  __builtin_amdgcn_sched_barrier(0);

#pragma unroll
  for (int kt = 0; kt < NT; ++kt) {
    if (kt < NT - 3) {
      const char* gk = ktiles + (size_t)(kt + 3) * 16384 + stoff;
      char* dst = kst + ((kt + 3) & 3) * 16384 + ldoff;
      gll16(gk, dst);
      gll16(gk + 8192, dst + 8192);
    }
    __builtin_amdgcn_sched_barrier(0);
    unsigned long long c0 = ma0, c1 = ma1, c2 = ma2, c3 = ma3;
    if (kt < NT - 1) {
      ma0 = bmr[kt + 1]; ma1 = bmr[NT + kt + 1];
      ma2 = bmr[2 * NT + kt + 1]; ma3 = bmr[3 * NT + kt + 1];
    }
    const char* kbc = kst + (kt & 3) * 16384;
    f32x4_t acc = {0.f, 0.f, 0.f, 0.f};
    __builtin_amdgcn_s_setprio(1);
#pragma unroll
    for (int kk = 0; kk < 4; ++kk) {
      short8_t bfr = *(const short8_t*)(kbc + krow * 256 + ((kk * 64 + lg * 16) ^ ((krow & 7) << 4)));
      acc = __builtin_amdgcn_mfma_f32_16x16x32_bf16(qf[kk], bfr, acc, 0, 0, 0);
    }
    __builtin_amdgcn_s_setprio(0);
    psum[0] += ((c0 >> bitp) & 1) ? __expf(acc[0] * SCALE) : 1.0f;
    psum[1] += ((c1 >> bitp) & 1) ? __expf(acc[1] * SCALE) : 1.0f;
    psum[2] += ((c2 >> bitp) & 1) ? __expf(acc[2] * SCALE) : 1.0f;
    psum[3] += ((c3 >> bitp) & 1) ? __expf(acc[3] * SCALE) : 1.0f;
    if (kt == 0) {
      asm volatile("s_waitcnt vmcnt(12) lgkmcnt(0)\n\ts_barrier" ::: "memory");
    } else if (kt <= 28) {
      asm volatile("s_waitcnt vmcnt(16) lgkmcnt(0)\n\ts_barrier" ::: "memory");
    } else if (kt == 29) {
      asm volatile("s_waitcnt vmcnt(14) lgkmcnt(0)\n\ts_barrier" ::: "memory");
    } else if (kt == 30) {
      asm volatile("s_waitcnt vmcnt(12) lgkmcnt(0)\n\ts_barrier" ::: "memory");
    }
    __builtin_amdgcn_sched_barrier(0);
  }

  // row sums -> rinv
#pragma unroll
  for (int off = 1; off < 16; off <<= 1) {
#pragma unroll
    for (int jj = 0; jj < 4; ++jj) psum[jj] += __shfl_xor(psum[jj], off, 64);
  }
  if (ln == 0) {
#pragma unroll
    for (int jj = 0; jj < 4; ++jj) lpart[kq * 32 + qh * 16 + lg * 4 + jj] = psum[jj];
  }
  __syncthreads();
  if (tid < 32)
    rinv[tid] = 1.0f / (lpart[tid] + lpart[32 + tid] + lpart[64 + tid] + lpart[96 + tid]);
  __syncthreads();

  // ===== pass 2: QK recompute + batched score stores + PV =====
  // Per-iter VMEM order (pinned): [gll(kt+1) x4][mask(kt+1) x4][lgkm barrier]
  // [if kt odd: 2 NT score stores (tiles kt-1,kt)][PV][end barrier].
  // End-of-iter wait retires gll(kt+1): newer ops = 4 masks (+2 stores on odd)
  // -> vmcnt(4) even / vmcnt(6) odd; none at kt=31 (no gll outstanding needed).
  // p~ triple-buffer: tile kt -> pb[kt%3]; score of (kt-1,kt) read at iter kt
  // never aliases iter kt+1's writes (buffers differ by 2 mod 3).
  char* kbb = kst;             // 2 x 16384 (K dbuf)
  char* vbb = kst + 32768;     // 2 x 16384 (V dbuf)
  const int sr = tid >> 4;
  const int shalf = (tid >> 3) & 1;          // which tile of the pair
  const int sc8 = (tid & 7) * 8;             // col within tile (8 fp32)
  const float ri_s = rinv[sr];
  float* scp = Sc + ((size_t)bh * S_LEN + q0 + sr) * S_LEN + (tid & 15) * 8;

  gll16(ktiles + stoff,        kbb + ldoff);
  gll16(ktiles + stoff + 8192, kbb + ldoff + 8192);
  gll16(vtiles + stoff,        vbb + ldoff);
  gll16(vtiles + stoff + 8192, vbb + ldoff + 8192);
  __builtin_amdgcn_sched_barrier(0);
  ma0 = bmr[0]; ma1 = bmr[NT]; ma2 = bmr[2 * NT]; ma3 = bmr[3 * NT];
  asm volatile("s_waitcnt vmcnt(4) lgkmcnt(0)\n\ts_barrier" ::: "memory");
  __builtin_amdgcn_sched_barrier(0);

  f32x4_t oacc0 = {0.f, 0.f, 0.f, 0.f}, oacc1 = {0.f, 0.f, 0.f, 0.f};

#pragma unroll 2
  for (int kt = 0; kt < NT; ++kt) {
    const int cur = kt & 1, nxt = cur ^ 1;
    if (kt < NT - 1) {
      const char* gk = ktiles + (size_t)(kt + 1) * 16384 + stoff;
      const char* gv = vtiles + (size_t)(kt + 1) * 16384 + stoff;
      gll16(gk,        kbb + nxt * 16384 + ldoff);
      gll16(gk + 8192, kbb + nxt * 16384 + ldoff + 8192);
      gll16(gv,        vbb + nxt * 16384 + ldoff);
      gll16(gv + 8192, vbb + nxt * 16384 + ldoff + 8192);
    }
    __builtin_amdgcn_sched_barrier(0);
    unsigned long long c0 = ma0, c1 = ma1, c2 = ma2, c3 = ma3;
    if (kt < NT - 1) {
      ma0 = bmr[kt + 1]; ma1 = bmr[NT + kt + 1];
      ma2 = bmr[2 * NT + kt + 1]; ma3 = bmr[3 * NT + kt + 1];
    }
    const char* kbc = kbb + cur * 16384;
    f32x4_t acc = {0.f, 0.f, 0.f, 0.f};
    __builtin_amdgcn_s_setprio(1);
#pragma unroll
    for (int kk = 0; kk < 4; ++kk) {
      short8_t bfr = *(const short8_t*)(kbc + krow * 256 + ((kk * 64 + lg * 16) ^ ((krow & 7) << 4)));
      acc = __builtin_amdgcn_mfma_f32_16x16x32_bf16(qf[kk], bfr, acc, 0, 0, 0);
    }
    __builtin_amdgcn_s_setprio(0);
    float p0 = ((c0 >> bitp) & 1) ? __expf(acc[0] * SCALE) : 1.0f;  // exp(1e-9)==1.0f
    float p1 = ((c1 >> bitp) & 1) ? __expf(acc[1] * SCALE) : 1.0f;
    float p2 = ((c2 >> bitp) & 1) ? __expf(acc[2] * SCALE) : 1.0f;
    float p3 = ((c3 >> bitp) & 1) ? __expf(acc[3] * SCALE) : 1.0f;
    unsigned short* pbc = pbB + (kt % 3) * 2304;
    pbc[pbase]       = f2bf(p0);
    pbc[pbase + 72]  = f2bf(p1);
    pbc[pbase + 144] = f2bf(p2);
    pbc[pbase + 216] = f2bf(p3);
    // publish p~ (LDS drain only; gll prefetch + mask loads stay in flight)
    asm volatile("s_waitcnt lgkmcnt(0)\n\ts_barrier" ::: "memory");
    __builtin_amdgcn_sched_barrier(0);
    // batched score write: on odd iters emit tiles (kt-1, kt) -> 512B rows
    if (kt & 1) {
      const unsigned short* pbs = pbB + ((kt - 1 + shalf) % 3) * 2304;
      short8_t pw = *(const short8_t*)&pbs[sr * 72 + sc8];
      f32x4_t s0 = { bf2f((unsigned short)pw[0]) * ri_s, bf2f((unsigned short)pw[1]) * ri_s,
                     bf2f((unsigned short)pw[2]) * ri_s, bf2f((unsigned short)pw[3]) * ri_s };
      f32x4_t s1 = { bf2f((unsigned short)pw[4]) * ri_s, bf2f((unsigned short)pw[5]) * ri_s,
                     bf2f((unsigned short)pw[6]) * ri_s, bf2f((unsigned short)pw[7]) * ri_s };
      float* dst = scp + (kt - 1) * 64;
      __builtin_nontemporal_store(s0, (f32x4_t*)dst);
      __builtin_nontemporal_store(s1, (f32x4_t*)(dst + 4));
    }
    // PV from p~ tile + V^T tile
    const char* vbc = vbb + cur * 16384;
    short8_t af0 = *(const short8_t*)((const char*)pbc + arow * 144 + lg * 16);
    short8_t af1 = *(const short8_t*)((const char*)pbc + arow * 144 + 64 + lg * 16);
    __builtin_amdgcn_s_setprio(1);
    {
      const int vr0 = kq * 32 + ln;
      short8_t bv0 = *(const short8_t*)(vbc + vr0 * 128 + ((lg * 16) ^ ((vr0 & 7) << 4)));
      short8_t bv1 = *(const short8_t*)(vbc + vr0 * 128 + ((64 + lg * 16) ^ ((vr0 & 7) << 4)));
      oacc0 = __builtin_amdgcn_mfma_f32_16x16x32_bf16(af0, bv0, oacc0, 0, 0, 0);
      oacc0 = __builtin_amdgcn_mfma_f32_16x16x32_bf16(af1, bv1, oacc0, 0, 0, 0);
    }
    {
      const int vr1 = kq * 32 + 16 + ln;
      short8_t bv0 = *(const short8_t*)(vbc + vr1 * 128 + ((lg * 16) ^ ((vr1 & 7) << 4)));
      short8_t bv1 = *(const short8_t*)(vbc + vr1 * 128 + ((64 + lg * 16) ^ ((vr1 & 7) << 4)));
      oacc1 = __builtin_amdgcn_mfma_f32_16x16x32_bf16(af0, bv0, oacc1, 0, 0, 0);
      oacc1 = __builtin_amdgcn_mfma_f32_16x16x32_bf16(af1, bv1, oacc1, 0, 0, 0);
    }
    __builtin_amdgcn_s_setprio(0);
    if (kt < NT - 1) {
      if (kt & 1) {
        asm volatile("s_waitcnt vmcnt(6) lgkmcnt(0)\n\ts_barrier" ::: "memory");
      } else {
        asm volatile("s_waitcnt vmcnt(4) lgkmcnt(0)\n\ts_barrier" ::: "memory");
      }
    }
    __builtin_amdgcn_sched_barrier(0);
  }

  // Out epilogue (nontemporal)
#pragma unroll
  for (int jj = 0; jj < 4; ++jj) {
    int row = qh * 16 + lg * 4 + jj;
    float ri = rinv[row];
    size_t o = ((size_t)bh * S_LEN + q0 + row) * DH + kq * 32 + ln;
    __builtin_nontemporal_store(oacc0[jj] * ri, &Out[o]);
    __builtin_nontemporal_store(oacc1[jj] * ri, &Out[o + 16]);
  }
}

// ---------------- round-1 kernel (fallback when ws too small) ----------------

#define PT_STRIDE 2056
#define KLDS_STRIDE 136
#define VT_STRIDE 72

__global__ __launch_bounds__(512, 1)
void sdpa_kernel_v1(const float* __restrict__ Q, const float* __restrict__ K,
                    const float* __restrict__ V, const int* __restrict__ M,
                    float* __restrict__ Out, float* __restrict__ Sc) {
  extern __shared__ char smem[];
  unsigned short* pt  = (unsigned short*)smem;
  unsigned short* kvb = (unsigned short*)(smem + 131584);
  float* lpart2 = (float*)(smem + 131584 + 18432);
  float* rinv2  = lpart2 + 128;

  const int tid  = threadIdx.x;
  const int lane = tid & 63;
  const int wid  = tid >> 6;
  const int qh = wid >> 2, kq = wid & 3;
  const int lg = lane >> 4, ln = lane & 15;

  const int bid = blockIdx.x;
  const int qt = bid & 63, bh = bid >> 6, b = bh >> 4;
  const int q0 = qt * 32;

  const float* Qb = Q + ((size_t)bh * S_LEN + q0) * DH;
  const float* Kb = K + (size_t)bh * S_LEN * DH;
  const float* Vb = V + (size_t)bh * S_LEN * DH;
  const int*   Mb = M + ((size_t)b * S_LEN + q0) * (size_t)S_LEN;

  short8_t qf[4];
  {
    const float* qrow = Qb + (qh * 16 + ln) * DH;
#pragma unroll
    for (int kk = 0; kk < 4; ++kk) {
      f32x4_t a = *(const f32x4_t*)(qrow + kk * 32 + lg * 8);
      f32x4_t c = *(const f32x4_t*)(qrow + kk * 32 + lg * 8 + 4);
      short8_t f;
#pragma unroll
      for (int jj = 0; jj < 4; ++jj) { f[jj] = (short)f2bf(a[jj]); f[4 + jj] = (short)f2bf(c[jj]); }
      qf[kk] = f;
    }
  }

  float psum[4] = {0.f, 0.f, 0.f, 0.f};

  for (int kt = 0; kt < 32; ++kt) {
    const int k0 = kt * 64;
    __syncthreads();
#pragma unroll
    for (int p = 0; p < 4; ++p) {
      int idx = (p << 11) | (tid << 2);
      int r = idx >> 7, d0 = idx & 127;
      f32x4_t val = *(const f32x4_t*)(Kb + (size_t)(k0 + r) * DH + d0);
      u16x4_t w = { f2bf(val[0]), f2bf(val[1]), f2bf(val[2]), f2bf(val[3]) };
      *(u16x4_t*)&kvb[r * KLDS_STRIDE + d0] = w;
    }
    __syncthreads();

    const int kcol = k0 + kq * 16 + ln;
    int mv[4];
#pragma unroll
    for (int jj = 0; jj < 4; ++jj)
      mv[jj] = Mb[(size_t)(qh * 16 + lg * 4 + jj) * S_LEN + kcol];

    f32x4_t acc = {0.f, 0.f, 0.f, 0.f};
#pragma unroll
    for (int kk = 0; kk < 4; ++kk) {
      short8_t bf = *(short8_t*)&kvb[(kq * 16 + ln) * KLDS_STRIDE + kk * 32 + lg * 8];
      acc = __builtin_amdgcn_mfma_f32_16x16x32_bf16(qf[kk], bf, acc, 0, 0, 0);
    }
#pragma unroll
    for (int jj = 0; jj < 4; ++jj) {
      float p = mv[jj] ? __expf(acc[jj] * SCALE) : 1.0f;
      psum[jj] += p;
      pt[(qh * 16 + lg * 4 + jj) * PT_STRIDE + kcol] = f2bf(p);
    }
  }

#pragma unroll
  for (int off = 1; off < 16; off <<= 1) {
#pragma unroll
    for (int jj = 0; jj < 4; ++jj) psum[jj] += __shfl_xor(psum[jj], off, 64);
  }
  if (ln == 0) {
#pragma unroll
    for (int jj = 0; jj < 4; ++jj) lpart2[kq * 32 + qh * 16 + lg * 4 + jj] = psum[jj];
  }
  __syncthreads();
  if (tid < 32)
    rinv2[tid] = 1.0f / (lpart2[tid] + lpart2[32 + tid] + lpart2[64 + tid] + lpart2[96 + tid]);
  __syncthreads();

  {
    float* srow = Sc + ((size_t)bh * S_LEN + q0) * (size_t)S_LEN;
#pragma unroll 4
    for (int r = 0; r < 32; ++r) {
      float ri = rinv2[r];
      u16x4_t w = *(u16x4_t*)&pt[r * PT_STRIDE + tid * 4];
      f32x4_t o = { bf2f(w[0]) * ri, bf2f(w[1]) * ri, bf2f(w[2]) * ri, bf2f(w[3]) * ri };
      *(f32x4_t*)(srow + (size_t)r * S_LEN + tid * 4) = o;
    }
  }

  const int dq = kq;
  f32x4_t oacc0 = {0.f,0.f,0.f,0.f}, oacc1 = {0.f,0.f,0.f,0.f};
  const int dcol = tid & 127, qq = tid >> 7;
  for (int vt = 0; vt < 32; ++vt) {
    const int k0 = vt * 64;
    __syncthreads();
#pragma unroll
    for (int p = 0; p < 4; ++p) {
      int krb = p * 16 + qq * 4;
      const float* vp = Vb + (size_t)(k0 + krb) * DH + dcol;
      float v0 = vp[0], v1 = vp[DH], v2 = vp[2 * DH], v3 = vp[3 * DH];
      u16x4_t w = { f2bf(v0), f2bf(v1), f2bf(v2), f2bf(v3) };
      *(u16x4_t*)&kvb[dcol * VT_STRIDE + krb] = w;
    }
    __syncthreads();
#pragma unroll
    for (int ks = 0; ks < 2; ++ks) {
      short8_t af = *(short8_t*)&pt[(qh * 16 + ln) * PT_STRIDE + k0 + ks * 32 + lg * 8];
#pragma unroll
      for (int nb = 0; nb < 2; ++nb) {
        short8_t bf = *(short8_t*)&kvb[(dq * 32 + nb * 16 + ln) * VT_STRIDE + ks * 32 + lg * 8];
        if (nb == 0) oacc0 = __builtin_amdgcn_mfma_f32_16x16x32_bf16(af, bf, oacc0, 0, 0, 0);
        else         oacc1 = __builtin_amdgcn_mfma_f32_16x16x32_bf16(af, bf, oacc1, 0, 0, 0);
      }
    }
  }
#pragma unroll
  for (int jj = 0; jj < 4; ++jj) {
    int row = qh * 16 + lg * 4 + jj;
    float ri = rinv2[row];
    size_t o = ((size_t)bh * S_LEN + q0 + row) * DH + dq * 32 + ln;
    Out[o]      = oacc0[jj] * ri;
    Out[o + 16] = oacc1[jj] * ri;
  }
}

// ---------------- launcher ----------------

extern "C" void kernel_launch(void* const* d_in, const int* in_sizes, int n_in,
                              void* d_out, int out_size, void* d_ws, size_t ws_size,
                              hipStream_t stream) {
  const float* q = (const float*)d_in[0];
  const float* k = (const float*)d_in[1];
  const float* v = (const float*)d_in[2];
  const int*   m = (const int*)d_in[3];
  float* out = (float*)d_out;
  float* sc  = out + (size_t)2 * 16 * S_LEN * DH;

  const size_t BM_BYTES = 1u << 20;
  const size_t KW_BYTES = (size_t)32 * 32 * 16384;  // 16 MiB
  const size_t NEED = BM_BYTES + 2 * KW_BYTES;      // ~33 MiB

  if (ws_size >= NEED) {
    unsigned long long* bm = (unsigned long long*)d_ws;
    unsigned short* kws = (unsigned short*)((char*)d_ws + BM_BYTES);
    unsigned short* vws = (unsigned short*)((char*)d_ws + BM_BYTES + KW_BYTES);

    pack_mask_k<<<dim3(2048), dim3(256), 0, stream>>>(m, bm);
    conv_k_k<<<dim3(4096), dim3(256), 0, stream>>>(k, kws);
    conv_v_k<<<dim3(1024), dim3(256), 0, stream>>>(v, vws);

    const int smem = 65536 + 13824 + 512 + 128;  // 80000
    hipFuncSetAttribute((const void*)sdpa_fused,
                        hipFuncAttributeMaxDynamicSharedMemorySize, smem);
    sdpa_fused<<<dim3(2048), dim3(512), smem, stream>>>(q, kws, vws, bm, out, sc);
  } else {
    const int smem = 131584 + 18432 + 512 + 128;
    hipFuncSetAttribute((const void*)sdpa_kernel_v1,
                        hipFuncAttributeMaxDynamicSharedMemorySize, smem);
    sdpa_kernel_v1<<<dim3(2048), dim3(512), smem, stream>>>(q, k, v, m, out, sc);
  }
}